// Round 4
// baseline (507.654 us; speedup 1.0000x reference)
//
#include <hip/hip_runtime.h>
#include <hip/hip_bf16.h>

#define EPS_ 1e-5f

typedef __attribute__((ext_vector_type(8))) short bf16x8;
typedef __attribute__((ext_vector_type(4))) float f32x4;

static __device__ __forceinline__ float bf2f(unsigned short u) {
  return __uint_as_float(((unsigned int)u) << 16);
}
static __device__ __forceinline__ unsigned short f2bf(float f) {
  unsigned int u = __float_as_uint(f);
  u += 0x7FFFu + ((u >> 16) & 1u);   // RNE
  return (unsigned short)(u >> 16);
}

// tanh-form GELU: branch-free, 1 transcendental
static __device__ __forceinline__ float gelu_fast(float z) {
  float y = 0.7978845608028654f * (z + 0.044715f * z * z * z);
  float e = __expf(2.f * y);
  float t = 1.f - 2.f / (1.f + e);   // tanh(y), saturates correctly at +-inf
  return 0.5f * z * (1.f + t);
}

// checked: load 4 bf16 at column gj (4-aligned); zero-fill OOB
static __device__ __forceinline__ void ld4z(const unsigned short* rowptr,
                                            int gj, bool vrow, float* dst) {
  if (vrow && (unsigned)gj < 768u) {
    ushort4 u = *(const ushort4*)(rowptr + gj);
    dst[0] = bf2f(u.x); dst[1] = bf2f(u.y); dst[2] = bf2f(u.z); dst[3] = bf2f(u.w);
  } else {
    dst[0] = 0.f; dst[1] = 0.f; dst[2] = 0.f; dst[3] = 0.f;
  }
}

// checked window cols jc-1 .. jc+8 -> w10[0..9]
static __device__ __forceinline__ void loadrow10(const unsigned short* rowptr,
                                                 bool vrow, int jc, float* w10) {
  float q[4];
  ld4z(rowptr, jc - 4, vrow, q);
  w10[0] = q[3];
  ld4z(rowptr, jc, vrow, q);
  w10[1] = q[0]; w10[2] = q[1]; w10[3] = q[2]; w10[4] = q[3];
  ld4z(rowptr, jc + 4, vrow, q);
  w10[5] = q[0]; w10[6] = q[1]; w10[7] = q[2]; w10[8] = q[3];
  ld4z(rowptr, jc + 8, vrow, q);
  w10[9] = q[0];
}

// unchecked fast window: 3 loads, 10 cvts; returns interior 8 raw bf16
static __device__ __forceinline__ bf16x8 ldrow10f(const unsigned short* p,
                                                  float* w) {
  ushort4 aa = *(const ushort4*)(p - 4);
  bf16x8 bb = *(const bf16x8*)(p);
  ushort4 cc = *(const ushort4*)(p + 8);
  w[0] = bf2f(aa.w);
#pragma unroll
  for (int e = 0; e < 8; ++e) w[1 + e] = bf2f((unsigned short)bb[e]);
  w[9] = bf2f(cc.x);
  return bb;
}

static __device__ __forceinline__ bf16x8 packrow(const float* w1) {
  bf16x8 r;
#pragma unroll
  for (int e = 0; e < 8; ++e) r[e] = (short)f2bf(w1[1 + e]);
  return r;
}

// ---------------------------------------------------------------------------
// K1: a[b,l,d] = sum_e x[b,l,e] * W_sl[d,e] + b_sl[d]  -> bf16
// ---------------------------------------------------------------------------
__global__ __launch_bounds__(256) void k1_proj(
    const float* __restrict__ x, const float* __restrict__ Wsl,
    const float* __restrict__ bsl, unsigned short* __restrict__ abf) {
  __shared__ float xr[1024];
  __shared__ float red[256];
  const int bl = blockIdx.x;
  const int tid = threadIdx.x;
  for (int idx = tid; idx < 1024; idx += 256)
    xr[idx] = x[(size_t)bl * 1024 + idx];
  __syncthreads();
  const int d = tid & 63, q = tid >> 6;
  const float* w = Wsl + (size_t)d * 1024 + q * 256;
  const float* xq = &xr[q * 256];
  float s = 0.f;
#pragma unroll 8
  for (int e = 0; e < 256; ++e) s += w[e] * xq[e];
  red[tid] = s;
  __syncthreads();
  if (tid < 64) {
    float v = red[tid] + red[64 + tid] + red[128 + tid] + red[192 + tid] + bsl[tid];
    abf[(size_t)bl * 64 + tid] = f2bf(v);
  }
}

// ---------------------------------------------------------------------------
// K2 (MFMA): per (b,i, jblk of 64): outer-proj + LN + residual -> xp (bf16)
// ---------------------------------------------------------------------------
__global__ __launch_bounds__(256) void k2_outer(
    const float* __restrict__ xpw, const unsigned short* __restrict__ abf,
    const float* __restrict__ Wop, const float* __restrict__ bop,
    const float* __restrict__ lnw, const float* __restrict__ lnb,
    unsigned short* __restrict__ xp) {
  __shared__ __align__(16) unsigned short Vt[64 * 72];  // [c][d] bf16
  __shared__ __align__(16) unsigned short Lt[64 * 72];  // [c][j] bf16
  __shared__ float ail[64];
  __shared__ float bopl[64], lnwl[64], lnbl[64];
  const int tid = threadIdx.x;
  const int bx = blockIdx.x;
  const int jblk = bx % 12;
  const int i = (bx / 12) % 768;
  const int b = bx / (12 * 768);
  const int jb = jblk * 64;

  if (tid < 64) ail[tid] = bf2f(abf[(size_t)(b * 768 + i) * 64 + tid]);
  else if (tid < 128) bopl[tid - 64] = bop[tid - 64];
  else if (tid < 192) lnwl[tid - 128] = lnw[tid - 128];
  else lnbl[tid - 192] = lnb[tid - 192];
  __syncthreads();

  {  // build Vt
    const int c = tid >> 2, d0 = (tid & 3) << 4;
    const float4* wr = (const float4*)&Wop[c * 64 + d0];
#pragma unroll
    for (int t = 0; t < 4; ++t) {
      float4 w4 = wr[t];
      ushort4 u = make_ushort4(f2bf(w4.x * ail[d0 + 4 * t]),
                               f2bf(w4.y * ail[d0 + 4 * t + 1]),
                               f2bf(w4.z * ail[d0 + 4 * t + 2]),
                               f2bf(w4.w * ail[d0 + 4 * t + 3]));
      *(ushort4*)&Vt[c * 72 + d0 + 4 * t] = u;
    }
  }
  __syncthreads();

  const int lane = tid & 63, wv = tid >> 6;
  const int g = lane >> 4, l15 = lane & 15;
  f32x4 acc[4];
#pragma unroll
  for (int t = 0; t < 4; ++t) acc[t] = (f32x4){0.f, 0.f, 0.f, 0.f};

  const size_t arow = (size_t)(b * 768 + jb + wv * 16 + l15) * 64;
#pragma unroll
  for (int kk = 0; kk < 2; ++kk) {
    bf16x8 av = *(const bf16x8*)&abf[arow + kk * 32 + g * 8];
#pragma unroll
    for (int t = 0; t < 4; ++t) {
      bf16x8 bv = *(const bf16x8*)&Vt[(t * 16 + l15) * 72 + kk * 32 + g * 8];
      acc[t] = __builtin_amdgcn_mfma_f32_16x16x32_bf16(av, bv, acc[t], 0, 0, 0);
    }
  }

  float lw[4], lb[4], bo[4];
#pragma unroll
  for (int t = 0; t < 4; ++t) {
    lw[t] = lnwl[t * 16 + l15];
    lb[t] = lnbl[t * 16 + l15];
    bo[t] = bopl[t * 16 + l15];
  }
  float s1[4] = {0.f, 0.f, 0.f, 0.f}, s2[4] = {0.f, 0.f, 0.f, 0.f};
#pragma unroll
  for (int t = 0; t < 4; ++t)
#pragma unroll
    for (int q = 0; q < 4; ++q) {
      float v = acc[t][q] + bo[t];
      acc[t][q] = v;
      s1[q] += v;
      s2[q] += v * v;
    }
#pragma unroll
  for (int m = 1; m <= 8; m <<= 1)
#pragma unroll
    for (int q = 0; q < 4; ++q) {
      s1[q] += __shfl_xor(s1[q], m);
      s2[q] += __shfl_xor(s2[q], m);
    }
  float mean[4], rs[4];
#pragma unroll
  for (int q = 0; q < 4; ++q) {
    mean[q] = s1[q] * (1.f / 64.f);
    float var = s2[q] * (1.f / 64.f) - mean[q] * mean[q];
    rs[q] = rsqrtf(var + EPS_);
  }
#pragma unroll
  for (int t = 0; t < 4; ++t) {
    ushort4 u;
    unsigned short* up = (unsigned short*)&u;
#pragma unroll
    for (int q = 0; q < 4; ++q)
      up[q] = f2bf((acc[t][q] - mean[q]) * rs[q] * lw[t] + lb[t]);
    *(ushort4*)&Lt[(t * 16 + l15) * 72 + wv * 16 + g * 4] = u;
  }
  __syncthreads();

  {  // coalesced residual epilogue
    const int c = tid >> 2, jq = tid & 3;
    const size_t gbase = ((size_t)(b * 64 + c) * 768 + i) * 768 + jb + jq * 16;
    float vals[16];
#pragma unroll
    for (int h = 0; h < 2; ++h) {
      bf16x8 lv = *(const bf16x8*)&Lt[c * 72 + jq * 16 + h * 8];
#pragma unroll
      for (int e = 0; e < 8; ++e)
        vals[h * 8 + e] = bf2f((unsigned short)lv[e]);
    }
#pragma unroll
    for (int v4 = 0; v4 < 4; ++v4) {
      float4 xv = *(const float4*)&xpw[gbase + v4 * 4];
      ushort4 u = make_ushort4(f2bf(xv.x + vals[v4 * 4]),
                               f2bf(xv.y + vals[v4 * 4 + 1]),
                               f2bf(xv.z + vals[v4 * 4 + 2]),
                               f2bf(xv.w + vals[v4 * 4 + 3]));
      *(ushort4*)&xp[gbase + v4 * 4] = u;
    }
  }
}

// ---------------------------------------------------------------------------
// K3: GN stats from dwconv3x3(xp): 16-row slabs, register sliding window.
// grid = 2*64*12 = 1536, 384 threads
// ---------------------------------------------------------------------------
__global__ __launch_bounds__(384) void k3_stats(
    const unsigned short* __restrict__ xp, const float* __restrict__ dww,
    float* __restrict__ stats) {
  const int tid = threadIdx.x;
  const int bx = blockIdx.x;
  const int it = bx % 12;
  const int c = (bx / 12) & 63;
  const int b = bx / (12 * 64);
  const int q = tid % 96;
  const int half = tid / 96;
  const int i0 = it * 64 + half * 16;
  const int jc = q * 8;
  const unsigned short* base = xp + (size_t)(b * 64 + c) * 768 * 768;
  float w[9];
#pragma unroll
  for (int k = 0; k < 9; ++k) w[k] = dww[c * 9 + k];

  float w0[10], w1[10], w2[10];
  loadrow10(base + (size_t)(i0 - 1) * 768, (i0 - 1) >= 0, jc, w0);
  loadrow10(base + (size_t)i0 * 768, true, jc, w1);
  float s1 = 0.f, s2 = 0.f;
#pragma unroll
  for (int rr = 0; rr < 16; ++rr) {
    const int gi = i0 + rr + 1;
    loadrow10(base + (size_t)gi * 768, gi < 768, jc, w2);
#pragma unroll
    for (int jj = 0; jj < 8; ++jj) {
      float h = w[0] * w0[jj] + w[1] * w0[jj + 1] + w[2] * w0[jj + 2] +
                w[3] * w1[jj] + w[4] * w1[jj + 1] + w[5] * w1[jj + 2] +
                w[6] * w2[jj] + w[7] * w2[jj + 1] + w[8] * w2[jj + 2];
      s1 += h;
      s2 += h * h;
    }
#pragma unroll
    for (int t = 0; t < 10; ++t) { w0[t] = w1[t]; w1[t] = w2[t]; }
  }
#pragma unroll
  for (int off = 32; off >= 1; off >>= 1) {
    s1 += __shfl_xor(s1, off);
    s2 += __shfl_xor(s2, off);
  }
  __shared__ float ws1[6], ws2[6];
  const int wid = tid >> 6;
  if ((tid & 63) == 0) { ws1[wid] = s1; ws2[wid] = s2; }
  __syncthreads();
  if (tid == 0) {
    float t1 = 0.f, t2 = 0.f;
#pragma unroll
    for (int k = 0; k < 6; ++k) { t1 += ws1[k]; t2 += ws2[k]; }
    const int grp = c >> 1;
    atomicAdd(&stats[(b * 32 + grp) * 2 + 0], t1);
    atomicAdd(&stats[(b * 32 + grp) * 2 + 1], t2);
  }
}

// ---------------------------------------------------------------------------
// K3b: per (b,c) GN scale/bias
// ---------------------------------------------------------------------------
__global__ void k3b_affine(const float* __restrict__ stats,
                           const float* __restrict__ gnw,
                           const float* __restrict__ gnb,
                           float* __restrict__ af) {
  int tid = threadIdx.x;
  if (tid >= 128) return;
  int b = tid >> 6, c = tid & 63, g = c >> 1;
  float s1 = stats[(b * 32 + g) * 2];
  float s2 = stats[(b * 32 + g) * 2 + 1];
  const float N = 2.f * 768.f * 768.f;
  float m = s1 / N;
  float v = s2 / N - m * m;
  float rs = rsqrtf(v + EPS_);
  float A = rs * gnw[c];
  af[(b * 64 + c) * 2] = A;
  af[(b * 64 + c) * 2 + 1] = gnb[c] - m * A;
}

// ---------------------------------------------------------------------------
// K4 phase-1 body: dwconv + GN affine + fast GELU -> gT; retains xp rows.
// ---------------------------------------------------------------------------
template <bool FAST>
static __device__ __forceinline__ void k4_phase1(
    const unsigned short* base, int i0, int jc, const float* w, float A,
    float Bv, int swzc, unsigned short* gT, int q, bf16x8* raw) {
  float w0[10], w1[10], w2[10];
  if (FAST) {
    ldrow10f(base + (size_t)(i0 - 1) * 768 + jc, w0);
    raw[0] = ldrow10f(base + (size_t)i0 * 768 + jc, w1);
  } else {
    loadrow10(base + (size_t)(i0 - 1) * 768, i0 >= 1, jc, w0);
    loadrow10(base + (size_t)i0 * 768, true, jc, w1);
    raw[0] = packrow(w1);
  }
#pragma unroll
  for (int r = 0; r < 4; ++r) {
    const int gi = i0 + r + 1;
    if (FAST) {
      bf16x8 rw = ldrow10f(base + (size_t)gi * 768 + jc, w2);
      if (r < 3) raw[r + 1] = rw;
    } else {
      loadrow10(base + (size_t)gi * 768, gi < 768, jc, w2);
      if (r < 3) raw[r + 1] = packrow(w2);
    }
#pragma unroll
    for (int jj = 0; jj < 8; ++jj) {
      float h = w[0] * w0[jj] + w[1] * w0[jj + 1] + w[2] * w0[jj + 2] +
                w[3] * w1[jj] + w[4] * w1[jj + 1] + w[5] * w1[jj + 2] +
                w[6] * w2[jj] + w[7] * w2[jj + 1] + w[8] * w2[jj + 2];
      float z = A * h + Bv;
      const int p = r * 64 + q * 8 + jj;
      gT[p * 72 + swzc] = f2bf(gelu_fast(z));
    }
#pragma unroll
    for (int t = 0; t < 10; ++t) { w0[t] = w1[t]; w1[t] = w2[t]; }
  }
}

// ---------------------------------------------------------------------------
// K4 v4: tile = 4 rows x 64 cols, all 64 ch. 512 threads, 3 blocks/CU.
//   phase1: (c,q) coalesced dwconv + GN + fast GELU -> gT (swizzled);
//           retains interior xp rows in registers
//   phase2: 1x1 conv via MFMA
//   phase2b: conv result (bf16) -> oT[co][264] (gT memory reused)
//   phase3: out = xp(reg) + conv(oT) + bias, coalesced 32B/lane stores
// grid = 2*192*12 = 4608
// ---------------------------------------------------------------------------
__global__ __launch_bounds__(512, 6) void k4_final(
    const unsigned short* __restrict__ xp, const float* __restrict__ af,
    const float* __restrict__ dww, const float* __restrict__ pww,
    const float* __restrict__ pwb, float* __restrict__ out) {
  __shared__ __align__(16) unsigned short gT[256 * 72];  // phase3: oT[64][264]
  __shared__ __align__(16) unsigned short pwF[64 * 72];  // [co][ci]
  __shared__ float dwl[576];
  __shared__ float afl[128];
  __shared__ float pwbl[64];
  const int tid = threadIdx.x;
  const int bx = blockIdx.x;
  const int jt = bx % 12;
  const int it = (bx / 12) % 192;
  const int b = bx / (12 * 192);
  const int i0 = it * 4, j0 = jt * 64;

  {  // stage pwF (bf16)
    const int co = tid >> 3, ci0 = (tid & 7) * 8;
    float4 f0 = *(const float4*)&pww[co * 64 + ci0];
    float4 f1 = *(const float4*)&pww[co * 64 + ci0 + 4];
    *(ushort4*)&pwF[co * 72 + ci0] =
        make_ushort4(f2bf(f0.x), f2bf(f0.y), f2bf(f0.z), f2bf(f0.w));
    *(ushort4*)&pwF[co * 72 + ci0 + 4] =
        make_ushort4(f2bf(f1.x), f2bf(f1.y), f2bf(f1.z), f2bf(f1.w));
  }
  for (int idx = tid; idx < 576; idx += 512) dwl[idx] = dww[idx];
  if (tid < 128) afl[tid] = af[b * 128 + tid];
  if (tid < 64) pwbl[tid] = pwb[tid];
  __syncthreads();

  const int c = tid >> 3, q = tid & 7;
  bf16x8 raw[4];
  {  // phase 1
    const float* w = &dwl[c * 9];
    const float A = afl[c * 2], Bv = afl[c * 2 + 1];
    const unsigned short* base = xp + (size_t)(b * 64 + c) * 768 * 768;
    const int jc = j0 + q * 8;
    const int swzc = (((c >> 3) ^ q) << 3) + (c & 7);
    if (it >= 1 && it <= 190 && jt >= 1 && jt <= 10)
      k4_phase1<true>(base, i0, jc, w, A, Bv, swzc, gT, q, raw);
    else
      k4_phase1<false>(base, i0, jc, w, A, Bv, swzc, gT, q, raw);
  }
  __syncthreads();

  // phase 2: MFMA 1x1.  D[pixel][co], A = gT (swizzled chunks), B = pwF
  const int lane = tid & 63, wv = tid >> 6;
  const int g = lane >> 4, l15 = lane & 15;
  f32x4 acc[2][4];
#pragma unroll
  for (int mt = 0; mt < 2; ++mt)
#pragma unroll
    for (int nt = 0; nt < 4; ++nt) acc[mt][nt] = (f32x4){0.f, 0.f, 0.f, 0.f};

#pragma unroll
  for (int kk = 0; kk < 2; ++kk) {
    const int p0 = wv * 32 + l15;
    const int p1 = p0 + 16;
    const int cc0 = (4 * kk + g) ^ ((p0 >> 3) & 7);
    const int cc1 = (4 * kk + g) ^ ((p1 >> 3) & 7);
    bf16x8 a0 = *(const bf16x8*)&gT[p0 * 72 + cc0 * 8];
    bf16x8 a1 = *(const bf16x8*)&gT[p1 * 72 + cc1 * 8];
#pragma unroll
    for (int nt = 0; nt < 4; ++nt) {
      bf16x8 bv = *(const bf16x8*)&pwF[(nt * 16 + l15) * 72 + kk * 32 + g * 8];
      acc[0][nt] = __builtin_amdgcn_mfma_f32_16x16x32_bf16(a0, bv, acc[0][nt], 0, 0, 0);
      acc[1][nt] = __builtin_amdgcn_mfma_f32_16x16x32_bf16(a1, bv, acc[1][nt], 0, 0, 0);
    }
  }
  __syncthreads();  // all gT reads done before oT overwrite

  // phase 2b: conv results -> oT[co][264] (bf16), reusing gT memory
  unsigned short* oT = gT;
#pragma unroll
  for (int mt = 0; mt < 2; ++mt) {
#pragma unroll
    for (int nt = 0; nt < 4; ++nt) {
      const int co = nt * 16 + l15;
      const int p0 = wv * 32 + mt * 16 + g * 4;
      f32x4 a = acc[mt][nt];
      ushort4 u = make_ushort4(f2bf(a[0]), f2bf(a[1]), f2bf(a[2]), f2bf(a[3]));
      *(ushort4*)&oT[co * 264 + p0] = u;
    }
  }
  __syncthreads();

  // phase 3: out = xp(reg) + conv(oT) + bias
  {
    const float pb = pwbl[c];
    const size_t rowbase = ((size_t)(b * 64 + c) * 768 + i0) * 768 + j0 + q * 8;
#pragma unroll
    for (int r = 0; r < 4; ++r) {
      bf16x8 cv = *(const bf16x8*)&oT[c * 264 + r * 64 + q * 8];
      bf16x8 xv = raw[r];
      float4 o0, o1;
      o0.x = bf2f((unsigned short)xv[0]) + bf2f((unsigned short)cv[0]) + pb;
      o0.y = bf2f((unsigned short)xv[1]) + bf2f((unsigned short)cv[1]) + pb;
      o0.z = bf2f((unsigned short)xv[2]) + bf2f((unsigned short)cv[2]) + pb;
      o0.w = bf2f((unsigned short)xv[3]) + bf2f((unsigned short)cv[3]) + pb;
      o1.x = bf2f((unsigned short)xv[4]) + bf2f((unsigned short)cv[4]) + pb;
      o1.y = bf2f((unsigned short)xv[5]) + bf2f((unsigned short)cv[5]) + pb;
      o1.z = bf2f((unsigned short)xv[6]) + bf2f((unsigned short)cv[6]) + pb;
      o1.w = bf2f((unsigned short)xv[7]) + bf2f((unsigned short)cv[7]) + pb;
      float* op = out + rowbase + (size_t)r * 768;
      *(float4*)op = o0;
      *(float4*)(op + 4) = o1;
    }
  }
}

// ---------------------------------------------------------------------------
extern "C" void kernel_launch(void* const* d_in, const int* in_sizes, int n_in,
                              void* d_out, int out_size, void* d_ws,
                              size_t ws_size, hipStream_t stream) {
  const float* x_pw = (const float*)d_in[0];
  const float* x    = (const float*)d_in[1];
  const float* Wsl  = (const float*)d_in[2];
  const float* bsl  = (const float*)d_in[3];
  const float* Wop  = (const float*)d_in[4];
  const float* bop  = (const float*)d_in[5];
  const float* lnw  = (const float*)d_in[6];
  const float* lnb  = (const float*)d_in[7];
  const float* dww  = (const float*)d_in[8];
  const float* gnw  = (const float*)d_in[9];
  const float* gnb  = (const float*)d_in[10];
  const float* pww  = (const float*)d_in[11];
  const float* pwb  = (const float*)d_in[12];
  float* out = (float*)d_out;

  char* ws = (char*)d_ws;
  unsigned short* a_bf = (unsigned short*)ws;             // 196608 B
  float* stats  = (float*)(ws + 196608);                  // 512 B
  float* affine = (float*)(ws + 197120);                  // 1024 B
  unsigned short* xpbuf = (unsigned short*)(ws + 262144); // 151 MB bf16

  hipMemsetAsync(stats, 0, 512, stream);
  k1_proj<<<2 * 768, 256, 0, stream>>>(x, Wsl, bsl, a_bf);
  k2_outer<<<2 * 768 * 12, 256, 0, stream>>>(x_pw, a_bf, Wop, bop, lnw, lnb,
                                             xpbuf);
  k3_stats<<<2 * 64 * 12, 384, 0, stream>>>(xpbuf, dww, stats);
  k3b_affine<<<1, 128, 0, stream>>>(stats, gnw, gnb, affine);
  k4_final<<<2 * 192 * 12, 512, 0, stream>>>(xpbuf, affine, dww, pww, pwb, out);
}

// Round 5
// 483.105 us; speedup vs baseline: 1.0508x; 1.0508x over previous
//
#include <hip/hip_runtime.h>
#include <hip/hip_bf16.h>

#define EPS_ 1e-5f

typedef __attribute__((ext_vector_type(8))) short bf16x8;
typedef __attribute__((ext_vector_type(4))) float f32x4;

static __device__ __forceinline__ float bf2f(unsigned short u) {
  return __uint_as_float(((unsigned int)u) << 16);
}
static __device__ __forceinline__ unsigned short f2bf(float f) {
  unsigned int u = __float_as_uint(f);
  u += 0x7FFFu + ((u >> 16) & 1u);   // RNE
  return (unsigned short)(u >> 16);
}

// tanh-form GELU: branch-free, 1 transcendental
static __device__ __forceinline__ float gelu_fast(float z) {
  float y = 0.7978845608028654f * (z + 0.044715f * z * z * z);
  float e = __expf(2.f * y);
  float t = 1.f - 2.f / (1.f + e);   // tanh(y), saturates correctly at +-inf
  return 0.5f * z * (1.f + t);
}

// checked: load 4 bf16 at column gj (4-aligned); zero-fill OOB
static __device__ __forceinline__ void ld4z(const unsigned short* rowptr,
                                            int gj, bool vrow, float* dst) {
  if (vrow && (unsigned)gj < 768u) {
    ushort4 u = *(const ushort4*)(rowptr + gj);
    dst[0] = bf2f(u.x); dst[1] = bf2f(u.y); dst[2] = bf2f(u.z); dst[3] = bf2f(u.w);
  } else {
    dst[0] = 0.f; dst[1] = 0.f; dst[2] = 0.f; dst[3] = 0.f;
  }
}

// checked window cols jc-1 .. jc+8 -> w10[0..9]
static __device__ __forceinline__ void loadrow10(const unsigned short* rowptr,
                                                 bool vrow, int jc, float* w10) {
  float q[4];
  ld4z(rowptr, jc - 4, vrow, q);
  w10[0] = q[3];
  ld4z(rowptr, jc, vrow, q);
  w10[1] = q[0]; w10[2] = q[1]; w10[3] = q[2]; w10[4] = q[3];
  ld4z(rowptr, jc + 4, vrow, q);
  w10[5] = q[0]; w10[6] = q[1]; w10[7] = q[2]; w10[8] = q[3];
  ld4z(rowptr, jc + 8, vrow, q);
  w10[9] = q[0];
}

// unchecked fast window: 3 loads, 10 cvts
static __device__ __forceinline__ void ldrow10f(const unsigned short* p,
                                                float* w) {
  ushort4 aa = *(const ushort4*)(p - 4);
  bf16x8 bb = *(const bf16x8*)(p);
  ushort4 cc = *(const ushort4*)(p + 8);
  w[0] = bf2f(aa.w);
#pragma unroll
  for (int e = 0; e < 8; ++e) w[1 + e] = bf2f((unsigned short)bb[e]);
  w[9] = bf2f(cc.x);
}

// ---------------------------------------------------------------------------
// K1: a[b,l,d] = sum_e x[b,l,e] * W_sl[d,e] + b_sl[d]  -> bf16
// ---------------------------------------------------------------------------
__global__ __launch_bounds__(256) void k1_proj(
    const float* __restrict__ x, const float* __restrict__ Wsl,
    const float* __restrict__ bsl, unsigned short* __restrict__ abf) {
  __shared__ float xr[1024];
  __shared__ float red[256];
  const int bl = blockIdx.x;
  const int tid = threadIdx.x;
  for (int idx = tid; idx < 1024; idx += 256)
    xr[idx] = x[(size_t)bl * 1024 + idx];
  __syncthreads();
  const int d = tid & 63, q = tid >> 6;
  const float* w = Wsl + (size_t)d * 1024 + q * 256;
  const float* xq = &xr[q * 256];
  float s = 0.f;
#pragma unroll 8
  for (int e = 0; e < 256; ++e) s += w[e] * xq[e];
  red[tid] = s;
  __syncthreads();
  if (tid < 64) {
    float v = red[tid] + red[64 + tid] + red[128 + tid] + red[192 + tid] + bsl[tid];
    abf[(size_t)bl * 64 + tid] = f2bf(v);
  }
}

// ---------------------------------------------------------------------------
// K2 v2 (MFMA, merged): block = (b,i); loop over 12 j-blocks of 64.
//   Vt[c][d] = ai[d]*W_op[c,d] staged ONCE per block (was 12x).
//   Per j-blk: D[j,c] = A[j,d]·Vt via mfma, +b_op, LN over c, residual -> xp
// grid = 2*768 = 1536 (fully resident), 256 threads
// ---------------------------------------------------------------------------
__global__ __launch_bounds__(256) void k2_outer(
    const float* __restrict__ xpw, const unsigned short* __restrict__ abf,
    const float* __restrict__ Wop, const float* __restrict__ bop,
    const float* __restrict__ lnw, const float* __restrict__ lnb,
    unsigned short* __restrict__ xp) {
  __shared__ __align__(16) unsigned short Vt[64 * 72];  // [c][d] bf16
  __shared__ __align__(16) unsigned short Lt[64 * 72];  // [c][j] bf16
  __shared__ float ail[64];
  __shared__ float bopl[64], lnwl[64], lnbl[64];
  const int tid = threadIdx.x;
  const int bl = blockIdx.x;
  const int i = bl % 768;
  const int b = bl / 768;

  if (tid < 64) ail[tid] = bf2f(abf[(size_t)(b * 768 + i) * 64 + tid]);
  else if (tid < 128) bopl[tid - 64] = bop[tid - 64];
  else if (tid < 192) lnwl[tid - 128] = lnw[tid - 128];
  else lnbl[tid - 192] = lnb[tid - 192];
  __syncthreads();

  {  // build Vt once
    const int c = tid >> 2, d0 = (tid & 3) << 4;
    const float4* wr = (const float4*)&Wop[c * 64 + d0];
#pragma unroll
    for (int t = 0; t < 4; ++t) {
      float4 w4 = wr[t];
      ushort4 u = make_ushort4(f2bf(w4.x * ail[d0 + 4 * t]),
                               f2bf(w4.y * ail[d0 + 4 * t + 1]),
                               f2bf(w4.z * ail[d0 + 4 * t + 2]),
                               f2bf(w4.w * ail[d0 + 4 * t + 3]));
      *(ushort4*)&Vt[c * 72 + d0 + 4 * t] = u;
    }
  }

  const int lane = tid & 63, wv = tid >> 6;
  const int g = lane >> 4, l15 = lane & 15;
  float lw[4], lb[4], bo[4];
  __syncthreads();
#pragma unroll
  for (int t = 0; t < 4; ++t) {
    lw[t] = lnwl[t * 16 + l15];
    lb[t] = lnbl[t * 16 + l15];
    bo[t] = bopl[t * 16 + l15];
  }
  const int ce = tid >> 2, jq = tid & 3;   // epilogue mapping

  for (int jblk = 0; jblk < 12; ++jblk) {
    const int jb = jblk * 64;
    f32x4 acc[4];
#pragma unroll
    for (int t = 0; t < 4; ++t) acc[t] = (f32x4){0.f, 0.f, 0.f, 0.f};

    const size_t arow = (size_t)(b * 768 + jb + wv * 16 + l15) * 64;
#pragma unroll
    for (int kk = 0; kk < 2; ++kk) {
      bf16x8 av = *(const bf16x8*)&abf[arow + kk * 32 + g * 8];
#pragma unroll
      for (int t = 0; t < 4; ++t) {
        bf16x8 bv = *(const bf16x8*)&Vt[(t * 16 + l15) * 72 + kk * 32 + g * 8];
        acc[t] = __builtin_amdgcn_mfma_f32_16x16x32_bf16(av, bv, acc[t], 0, 0, 0);
      }
    }

    float s1[4] = {0.f, 0.f, 0.f, 0.f}, s2[4] = {0.f, 0.f, 0.f, 0.f};
#pragma unroll
    for (int t = 0; t < 4; ++t)
#pragma unroll
      for (int q = 0; q < 4; ++q) {
        float v = acc[t][q] + bo[t];
        acc[t][q] = v;
        s1[q] += v;
        s2[q] += v * v;
      }
#pragma unroll
    for (int m = 1; m <= 8; m <<= 1)
#pragma unroll
      for (int q = 0; q < 4; ++q) {
        s1[q] += __shfl_xor(s1[q], m);
        s2[q] += __shfl_xor(s2[q], m);
      }
    float mean[4], rs[4];
#pragma unroll
    for (int q = 0; q < 4; ++q) {
      mean[q] = s1[q] * (1.f / 64.f);
      float var = s2[q] * (1.f / 64.f) - mean[q] * mean[q];
      rs[q] = rsqrtf(var + EPS_);
    }
    __syncthreads();  // prev-iter epilogue done reading Lt
#pragma unroll
    for (int t = 0; t < 4; ++t) {
      ushort4 u;
      unsigned short* up = (unsigned short*)&u;
#pragma unroll
      for (int q = 0; q < 4; ++q)
        up[q] = f2bf((acc[t][q] - mean[q]) * rs[q] * lw[t] + lb[t]);
      *(ushort4*)&Lt[(t * 16 + l15) * 72 + wv * 16 + g * 4] = u;
    }
    __syncthreads();

    {  // coalesced residual epilogue
      const size_t gbase = ((size_t)(b * 64 + ce) * 768 + i) * 768 + jb + jq * 16;
      float vals[16];
#pragma unroll
      for (int h = 0; h < 2; ++h) {
        bf16x8 lv = *(const bf16x8*)&Lt[ce * 72 + jq * 16 + h * 8];
#pragma unroll
        for (int e = 0; e < 8; ++e)
          vals[h * 8 + e] = bf2f((unsigned short)lv[e]);
      }
#pragma unroll
      for (int v4 = 0; v4 < 4; ++v4) {
        float4 xv = *(const float4*)&xpw[gbase + v4 * 4];
        ushort4 u = make_ushort4(f2bf(xv.x + vals[v4 * 4]),
                                 f2bf(xv.y + vals[v4 * 4 + 1]),
                                 f2bf(xv.z + vals[v4 * 4 + 2]),
                                 f2bf(xv.w + vals[v4 * 4 + 3]));
        *(ushort4*)&xp[gbase + v4 * 4] = u;
      }
    }
  }
}

// ---------------------------------------------------------------------------
// K3: GN stats from dwconv3x3(xp): 32-row slabs (round-3 version).
// grid = 2*64*24 = 3072, 384 threads
// ---------------------------------------------------------------------------
__global__ __launch_bounds__(384) void k3_stats(
    const unsigned short* __restrict__ xp, const float* __restrict__ dww,
    float* __restrict__ stats) {
  const int tid = threadIdx.x;
  const int bx = blockIdx.x;
  const int it = bx % 24;
  const int c = (bx / 24) & 63;
  const int b = bx / (24 * 64);
  const int q = tid % 96;
  const int half = tid / 96;
  const int i0 = it * 32 + half * 8;
  const int jc = q * 8;
  const unsigned short* base = xp + (size_t)(b * 64 + c) * 768 * 768;
  float w[9];
#pragma unroll
  for (int k = 0; k < 9; ++k) w[k] = dww[c * 9 + k];

  float w0[10], w1[10], w2[10];
  loadrow10(base + (size_t)(i0 - 1) * 768, (i0 - 1) >= 0, jc, w0);
  loadrow10(base + (size_t)i0 * 768, true, jc, w1);
  float s1 = 0.f, s2 = 0.f;
#pragma unroll
  for (int rr = 0; rr < 8; ++rr) {
    const int gi = i0 + rr + 1;
    loadrow10(base + (size_t)gi * 768, gi < 768, jc, w2);
#pragma unroll
    for (int jj = 0; jj < 8; ++jj) {
      float h = w[0] * w0[jj] + w[1] * w0[jj + 1] + w[2] * w0[jj + 2] +
                w[3] * w1[jj] + w[4] * w1[jj + 1] + w[5] * w1[jj + 2] +
                w[6] * w2[jj] + w[7] * w2[jj + 1] + w[8] * w2[jj + 2];
      s1 += h;
      s2 += h * h;
    }
#pragma unroll
    for (int t = 0; t < 10; ++t) { w0[t] = w1[t]; w1[t] = w2[t]; }
  }
#pragma unroll
  for (int off = 32; off >= 1; off >>= 1) {
    s1 += __shfl_xor(s1, off);
    s2 += __shfl_xor(s2, off);
  }
  __shared__ float ws1[6], ws2[6];
  const int wid = tid >> 6;
  if ((tid & 63) == 0) { ws1[wid] = s1; ws2[wid] = s2; }
  __syncthreads();
  if (tid == 0) {
    float t1 = 0.f, t2 = 0.f;
#pragma unroll
    for (int k = 0; k < 6; ++k) { t1 += ws1[k]; t2 += ws2[k]; }
    const int grp = c >> 1;
    atomicAdd(&stats[(b * 32 + grp) * 2 + 0], t1);
    atomicAdd(&stats[(b * 32 + grp) * 2 + 1], t2);
  }
}

// ---------------------------------------------------------------------------
// K3b: per (b,c) GN scale/bias
// ---------------------------------------------------------------------------
__global__ void k3b_affine(const float* __restrict__ stats,
                           const float* __restrict__ gnw,
                           const float* __restrict__ gnb,
                           float* __restrict__ af) {
  int tid = threadIdx.x;
  if (tid >= 128) return;
  int b = tid >> 6, c = tid & 63, g = c >> 1;
  float s1 = stats[(b * 32 + g) * 2];
  float s2 = stats[(b * 32 + g) * 2 + 1];
  const float N = 2.f * 768.f * 768.f;
  float m = s1 / N;
  float v = s2 / N - m * m;
  float rs = rsqrtf(v + EPS_);
  float A = rs * gnw[c];
  af[(b * 64 + c) * 2] = A;
  af[(b * 64 + c) * 2 + 1] = gnb[c] - m * A;
}

// ---------------------------------------------------------------------------
// K4 phase-1 body: dwconv + GN affine + fast GELU -> gT (no state retained)
// ---------------------------------------------------------------------------
template <bool FAST>
static __device__ __forceinline__ void k4_phase1(
    const unsigned short* base, int i0, int jc, const float* w, float A,
    float Bv, int swzc, unsigned short* gT, int q) {
  float w0[10], w1[10], w2[10];
  if (FAST) {
    ldrow10f(base + (size_t)(i0 - 1) * 768 + jc, w0);
    ldrow10f(base + (size_t)i0 * 768 + jc, w1);
  } else {
    loadrow10(base + (size_t)(i0 - 1) * 768, i0 >= 1, jc, w0);
    loadrow10(base + (size_t)i0 * 768, true, jc, w1);
  }
#pragma unroll
  for (int r = 0; r < 4; ++r) {
    const int gi = i0 + r + 1;
    if (FAST) {
      ldrow10f(base + (size_t)gi * 768 + jc, w2);
    } else {
      loadrow10(base + (size_t)gi * 768, gi < 768, jc, w2);
    }
#pragma unroll
    for (int jj = 0; jj < 8; ++jj) {
      float h = w[0] * w0[jj] + w[1] * w0[jj + 1] + w[2] * w0[jj + 2] +
                w[3] * w1[jj] + w[4] * w1[jj + 1] + w[5] * w1[jj + 2] +
                w[6] * w2[jj] + w[7] * w2[jj + 1] + w[8] * w2[jj + 2];
      float z = A * h + Bv;
      const int p = r * 64 + q * 8 + jj;
      gT[p * 72 + swzc] = f2bf(gelu_fast(z));
    }
#pragma unroll
    for (int t = 0; t < 10; ++t) { w0[t] = w1[t]; w1[t] = w2[t]; }
  }
}

// ---------------------------------------------------------------------------
// K4 v5: tile = 4 rows x 64 cols, all 64 ch. 512 threads, 3 blocks/CU.
//   phase1: (c,q) coalesced dwconv + GN + fast GELU -> gT (swizzled)
//   phase2: 1x1 conv via MFMA
//   phase2b: conv result (bf16) -> oT[co][264] (gT memory reused)
//   phase3: out = xp(global re-read, cache-hot) + conv(oT) + bias
// grid = 2*192*12 = 4608
// ---------------------------------------------------------------------------
__global__ __launch_bounds__(512, 6) void k4_final(
    const unsigned short* __restrict__ xp, const float* __restrict__ af,
    const float* __restrict__ dww, const float* __restrict__ pww,
    const float* __restrict__ pwb, float* __restrict__ out) {
  __shared__ __align__(16) unsigned short gT[256 * 72];  // phase3: oT[64][264]
  __shared__ __align__(16) unsigned short pwF[64 * 72];  // [co][ci]
  __shared__ float dwl[576];
  __shared__ float afl[128];
  __shared__ float pwbl[64];
  const int tid = threadIdx.x;
  const int bx = blockIdx.x;
  const int jt = bx % 12;
  const int it = (bx / 12) % 192;
  const int b = bx / (12 * 192);
  const int i0 = it * 4, j0 = jt * 64;

  {  // stage pwF (bf16)
    const int co = tid >> 3, ci0 = (tid & 7) * 8;
    float4 f0 = *(const float4*)&pww[co * 64 + ci0];
    float4 f1 = *(const float4*)&pww[co * 64 + ci0 + 4];
    *(ushort4*)&pwF[co * 72 + ci0] =
        make_ushort4(f2bf(f0.x), f2bf(f0.y), f2bf(f0.z), f2bf(f0.w));
    *(ushort4*)&pwF[co * 72 + ci0 + 4] =
        make_ushort4(f2bf(f1.x), f2bf(f1.y), f2bf(f1.z), f2bf(f1.w));
  }
  for (int idx = tid; idx < 576; idx += 512) dwl[idx] = dww[idx];
  if (tid < 128) afl[tid] = af[b * 128 + tid];
  if (tid < 64) pwbl[tid] = pwb[tid];
  __syncthreads();

  const int c = tid >> 3, q = tid & 7;
  {  // phase 1
    const float* w = &dwl[c * 9];
    const float A = afl[c * 2], Bv = afl[c * 2 + 1];
    const unsigned short* base = xp + (size_t)(b * 64 + c) * 768 * 768;
    const int jc = j0 + q * 8;
    const int swzc = (((c >> 3) ^ q) << 3) + (c & 7);
    if (it >= 1 && it <= 190 && jt >= 1 && jt <= 10)
      k4_phase1<true>(base, i0, jc, w, A, Bv, swzc, gT, q);
    else
      k4_phase1<false>(base, i0, jc, w, A, Bv, swzc, gT, q);
  }
  __syncthreads();

  // phase 2: MFMA 1x1.  D[pixel][co], A = gT (swizzled chunks), B = pwF
  const int lane = tid & 63, wv = tid >> 6;
  const int g = lane >> 4, l15 = lane & 15;
  f32x4 acc[2][4];
#pragma unroll
  for (int mt = 0; mt < 2; ++mt)
#pragma unroll
    for (int nt = 0; nt < 4; ++nt) acc[mt][nt] = (f32x4){0.f, 0.f, 0.f, 0.f};

#pragma unroll
  for (int kk = 0; kk < 2; ++kk) {
    const int p0 = wv * 32 + l15;
    const int p1 = p0 + 16;
    const int cc0 = (4 * kk + g) ^ ((p0 >> 3) & 7);
    const int cc1 = (4 * kk + g) ^ ((p1 >> 3) & 7);
    bf16x8 a0 = *(const bf16x8*)&gT[p0 * 72 + cc0 * 8];
    bf16x8 a1 = *(const bf16x8*)&gT[p1 * 72 + cc1 * 8];
#pragma unroll
    for (int nt = 0; nt < 4; ++nt) {
      bf16x8 bv = *(const bf16x8*)&pwF[(nt * 16 + l15) * 72 + kk * 32 + g * 8];
      acc[0][nt] = __builtin_amdgcn_mfma_f32_16x16x32_bf16(a0, bv, acc[0][nt], 0, 0, 0);
      acc[1][nt] = __builtin_amdgcn_mfma_f32_16x16x32_bf16(a1, bv, acc[1][nt], 0, 0, 0);
    }
  }
  __syncthreads();  // all gT reads done before oT overwrite

  // phase 2b: conv results -> oT[co][264] (bf16), reusing gT memory
  unsigned short* oT = gT;
#pragma unroll
  for (int mt = 0; mt < 2; ++mt) {
#pragma unroll
    for (int nt = 0; nt < 4; ++nt) {
      const int co = nt * 16 + l15;
      const int p0 = wv * 32 + mt * 16 + g * 4;
      f32x4 a = acc[mt][nt];
      ushort4 u = make_ushort4(f2bf(a[0]), f2bf(a[1]), f2bf(a[2]), f2bf(a[3]));
      *(ushort4*)&oT[co * 264 + p0] = u;
    }
  }
  __syncthreads();

  // phase 3: out = xp(global, cache-hot) + conv(oT) + bias
  {
    const float pb = pwbl[c];
    const size_t rowbase = ((size_t)(b * 64 + c) * 768 + i0) * 768 + j0 + q * 8;
#pragma unroll
    for (int r = 0; r < 4; ++r) {
      bf16x8 cv = *(const bf16x8*)&oT[c * 264 + r * 64 + q * 8];
      bf16x8 xv = *(const bf16x8*)(xp + rowbase + (size_t)r * 768);
      float4 o0, o1;
      o0.x = bf2f((unsigned short)xv[0]) + bf2f((unsigned short)cv[0]) + pb;
      o0.y = bf2f((unsigned short)xv[1]) + bf2f((unsigned short)cv[1]) + pb;
      o0.z = bf2f((unsigned short)xv[2]) + bf2f((unsigned short)cv[2]) + pb;
      o0.w = bf2f((unsigned short)xv[3]) + bf2f((unsigned short)cv[3]) + pb;
      o1.x = bf2f((unsigned short)xv[4]) + bf2f((unsigned short)cv[4]) + pb;
      o1.y = bf2f((unsigned short)xv[5]) + bf2f((unsigned short)cv[5]) + pb;
      o1.z = bf2f((unsigned short)xv[6]) + bf2f((unsigned short)cv[6]) + pb;
      o1.w = bf2f((unsigned short)xv[7]) + bf2f((unsigned short)cv[7]) + pb;
      float* op = out + rowbase + (size_t)r * 768;
      *(float4*)op = o0;
      *(float4*)(op + 4) = o1;
    }
  }
}

// ---------------------------------------------------------------------------
extern "C" void kernel_launch(void* const* d_in, const int* in_sizes, int n_in,
                              void* d_out, int out_size, void* d_ws,
                              size_t ws_size, hipStream_t stream) {
  const float* x_pw = (const float*)d_in[0];
  const float* x    = (const float*)d_in[1];
  const float* Wsl  = (const float*)d_in[2];
  const float* bsl  = (const float*)d_in[3];
  const float* Wop  = (const float*)d_in[4];
  const float* bop  = (const float*)d_in[5];
  const float* lnw  = (const float*)d_in[6];
  const float* lnb  = (const float*)d_in[7];
  const float* dww  = (const float*)d_in[8];
  const float* gnw  = (const float*)d_in[9];
  const float* gnb  = (const float*)d_in[10];
  const float* pww  = (const float*)d_in[11];
  const float* pwb  = (const float*)d_in[12];
  float* out = (float*)d_out;

  char* ws = (char*)d_ws;
  unsigned short* a_bf = (unsigned short*)ws;             // 196608 B
  float* stats  = (float*)(ws + 196608);                  // 512 B
  float* affine = (float*)(ws + 197120);                  // 1024 B
  unsigned short* xpbuf = (unsigned short*)(ws + 262144); // 151 MB bf16

  hipMemsetAsync(stats, 0, 512, stream);
  k1_proj<<<2 * 768, 256, 0, stream>>>(x, Wsl, bsl, a_bf);
  k2_outer<<<2 * 768, 256, 0, stream>>>(x_pw, a_bf, Wop, bop, lnw, lnb, xpbuf);
  k3_stats<<<2 * 64 * 24, 384, 0, stream>>>(xpbuf, dww, stats);
  k3b_affine<<<1, 128, 0, stream>>>(stats, gnw, gnb, affine);
  k4_final<<<2 * 192 * 12, 512, 0, stream>>>(xpbuf, affine, dww, pww, pwb, out);
}

// Round 6
// 449.527 us; speedup vs baseline: 1.1293x; 1.0747x over previous
//
#include <hip/hip_runtime.h>
#include <hip/hip_bf16.h>

#define EPS_ 1e-5f

typedef __attribute__((ext_vector_type(8))) short bf16x8;
typedef __attribute__((ext_vector_type(4))) float f32x4;

static __device__ __forceinline__ float bf2f(unsigned short u) {
  return __uint_as_float(((unsigned int)u) << 16);
}
static __device__ __forceinline__ unsigned short f2bf(float f) {
  unsigned int u = __float_as_uint(f);
  u += 0x7FFFu + ((u >> 16) & 1u);   // RNE
  return (unsigned short)(u >> 16);
}

// tanh-form GELU: branch-free, 1 transcendental
static __device__ __forceinline__ float gelu_fast(float z) {
  float y = 0.7978845608028654f * (z + 0.044715f * z * z * z);
  float e = __expf(2.f * y);
  float t = 1.f - 2.f / (1.f + e);   // tanh(y), saturates correctly at +-inf
  return 0.5f * z * (1.f + t);
}

// checked: load 4 bf16 at column gj (4-aligned); zero-fill OOB
static __device__ __forceinline__ void ld4z(const unsigned short* rowptr,
                                            int gj, bool vrow, float* dst) {
  if (vrow && (unsigned)gj < 768u) {
    ushort4 u = *(const ushort4*)(rowptr + gj);
    dst[0] = bf2f(u.x); dst[1] = bf2f(u.y); dst[2] = bf2f(u.z); dst[3] = bf2f(u.w);
  } else {
    dst[0] = 0.f; dst[1] = 0.f; dst[2] = 0.f; dst[3] = 0.f;
  }
}

// checked window cols jc-1 .. jc+8 -> w10[0..9]
static __device__ __forceinline__ void loadrow10(const unsigned short* rowptr,
                                                 bool vrow, int jc, float* w10) {
  float q[4];
  ld4z(rowptr, jc - 4, vrow, q);
  w10[0] = q[3];
  ld4z(rowptr, jc, vrow, q);
  w10[1] = q[0]; w10[2] = q[1]; w10[3] = q[2]; w10[4] = q[3];
  ld4z(rowptr, jc + 4, vrow, q);
  w10[5] = q[0]; w10[6] = q[1]; w10[7] = q[2]; w10[8] = q[3];
  ld4z(rowptr, jc + 8, vrow, q);
  w10[9] = q[0];
}

// unchecked fast window: 3 loads, 10 cvts; returns interior 8 raw bf16
static __device__ __forceinline__ bf16x8 ldrow10f(const unsigned short* p,
                                                  float* w) {
  ushort4 aa = *(const ushort4*)(p - 4);
  bf16x8 bb = *(const bf16x8*)(p);
  ushort4 cc = *(const ushort4*)(p + 8);
  w[0] = bf2f(aa.w);
#pragma unroll
  for (int e = 0; e < 8; ++e) w[1 + e] = bf2f((unsigned short)bb[e]);
  w[9] = bf2f(cc.x);
  return bb;
}

static __device__ __forceinline__ bf16x8 packrow(const float* w1) {
  bf16x8 r;
#pragma unroll
  for (int e = 0; e < 8; ++e) r[e] = (short)f2bf(w1[1 + e]);
  return r;
}

// ---------------------------------------------------------------------------
// K1 v2 (MFMA GEMM): a[m,d] = sum_e x[m,e]*W_sl[d,e] + b_sl[d] -> bf16
// M = B*L = 1536 rows; block = 64 rows, N=64, K=1024 in 4 chunks of 256.
// Coalesced staging (wave = one full row per iter). grid = 24, 256 thr.
// ---------------------------------------------------------------------------
__global__ __launch_bounds__(256) void k1_proj(
    const float* __restrict__ x, const float* __restrict__ Wsl,
    const float* __restrict__ bsl, unsigned short* __restrict__ abf) {
  __shared__ __align__(16) unsigned short xs[64 * 264];   // [row][k] bf16
  __shared__ __align__(16) unsigned short wsb[64 * 264];  // [d][k] bf16
  const int tid = threadIdx.x;
  const int bl = blockIdx.x;  // 0..23
  const int lane = tid & 63, wv = tid >> 6;
  const int g = lane >> 4, l15 = lane & 15;

  f32x4 acc[4];
#pragma unroll
  for (int nt = 0; nt < 4; ++nt) acc[nt] = (f32x4){0.f, 0.f, 0.f, 0.f};

  for (int k0 = 0; k0 < 1024; k0 += 256) {
    __syncthreads();
#pragma unroll
    for (int it = 0; it < 16; ++it) {
      const int idx = (it * 256 + tid) * 4;
      const int row = idx >> 8, col = idx & 255;
      float4 xv = *(const float4*)&x[(size_t)(bl * 64 + row) * 1024 + k0 + col];
      *(ushort4*)&xs[row * 264 + col] =
          make_ushort4(f2bf(xv.x), f2bf(xv.y), f2bf(xv.z), f2bf(xv.w));
      float4 wv4 = *(const float4*)&Wsl[(size_t)row * 1024 + k0 + col];
      *(ushort4*)&wsb[row * 264 + col] =
          make_ushort4(f2bf(wv4.x), f2bf(wv4.y), f2bf(wv4.z), f2bf(wv4.w));
    }
    __syncthreads();
#pragma unroll
    for (int kk = 0; kk < 8; ++kk) {
      bf16x8 av = *(const bf16x8*)&xs[(wv * 16 + l15) * 264 + kk * 32 + g * 8];
#pragma unroll
      for (int nt = 0; nt < 4; ++nt) {
        bf16x8 bv =
            *(const bf16x8*)&wsb[(nt * 16 + l15) * 264 + kk * 32 + g * 8];
        acc[nt] = __builtin_amdgcn_mfma_f32_16x16x32_bf16(av, bv, acc[nt], 0, 0, 0);
      }
    }
  }

#pragma unroll
  for (int nt = 0; nt < 4; ++nt) {
    const int d = nt * 16 + l15;
    const float bo = bsl[d];
#pragma unroll
    for (int qq = 0; qq < 4; ++qq) {
      const int m = wv * 16 + g * 4 + qq;
      abf[(size_t)(bl * 64 + m) * 64 + d] = f2bf(acc[nt][qq] + bo);
    }
  }
}

// ---------------------------------------------------------------------------
// K2 (MFMA, round-3 version): per (b,i, jblk of 64):
//   Vt[c][d] = ai[d]*W_op[c,d] (bf16, LDS);  D[j,c] = A[j,d]·Vt (mfma)
//   += b_op, LayerNorm over c -> Lt; coalesced residual epilogue -> xp bf16
// grid = 2*768*12 = 18432, 256 threads
// ---------------------------------------------------------------------------
__global__ __launch_bounds__(256) void k2_outer(
    const float* __restrict__ xpw, const unsigned short* __restrict__ abf,
    const float* __restrict__ Wop, const float* __restrict__ bop,
    const float* __restrict__ lnw, const float* __restrict__ lnb,
    unsigned short* __restrict__ xp) {
  __shared__ __align__(16) unsigned short Vt[64 * 72];  // [c][d] bf16
  __shared__ __align__(16) unsigned short Lt[64 * 72];  // [c][j] bf16
  __shared__ float ail[64];
  __shared__ float bopl[64], lnwl[64], lnbl[64];
  const int tid = threadIdx.x;
  const int bx = blockIdx.x;
  const int jblk = bx % 12;
  const int i = (bx / 12) % 768;
  const int b = bx / (12 * 768);
  const int jb = jblk * 64;

  if (tid < 64) ail[tid] = bf2f(abf[(size_t)(b * 768 + i) * 64 + tid]);
  else if (tid < 128) bopl[tid - 64] = bop[tid - 64];
  else if (tid < 192) lnwl[tid - 128] = lnw[tid - 128];
  else lnbl[tid - 192] = lnb[tid - 192];
  __syncthreads();

  {  // build Vt
    const int c = tid >> 2, d0 = (tid & 3) << 4;
    const float4* wr = (const float4*)&Wop[c * 64 + d0];
#pragma unroll
    for (int t = 0; t < 4; ++t) {
      float4 w4 = wr[t];
      ushort4 u = make_ushort4(f2bf(w4.x * ail[d0 + 4 * t]),
                               f2bf(w4.y * ail[d0 + 4 * t + 1]),
                               f2bf(w4.z * ail[d0 + 4 * t + 2]),
                               f2bf(w4.w * ail[d0 + 4 * t + 3]));
      *(ushort4*)&Vt[c * 72 + d0 + 4 * t] = u;
    }
  }
  __syncthreads();

  const int lane = tid & 63, wv = tid >> 6;
  const int g = lane >> 4, l15 = lane & 15;
  f32x4 acc[4];
#pragma unroll
  for (int t = 0; t < 4; ++t) acc[t] = (f32x4){0.f, 0.f, 0.f, 0.f};

  const size_t arow = (size_t)(b * 768 + jb + wv * 16 + l15) * 64;
#pragma unroll
  for (int kk = 0; kk < 2; ++kk) {
    bf16x8 av = *(const bf16x8*)&abf[arow + kk * 32 + g * 8];
#pragma unroll
    for (int t = 0; t < 4; ++t) {
      bf16x8 bv = *(const bf16x8*)&Vt[(t * 16 + l15) * 72 + kk * 32 + g * 8];
      acc[t] = __builtin_amdgcn_mfma_f32_16x16x32_bf16(av, bv, acc[t], 0, 0, 0);
    }
  }

  float lw[4], lb[4], bo[4];
#pragma unroll
  for (int t = 0; t < 4; ++t) {
    lw[t] = lnwl[t * 16 + l15];
    lb[t] = lnbl[t * 16 + l15];
    bo[t] = bopl[t * 16 + l15];
  }
  float s1[4] = {0.f, 0.f, 0.f, 0.f}, s2[4] = {0.f, 0.f, 0.f, 0.f};
#pragma unroll
  for (int t = 0; t < 4; ++t)
#pragma unroll
    for (int q = 0; q < 4; ++q) {
      float v = acc[t][q] + bo[t];
      acc[t][q] = v;
      s1[q] += v;
      s2[q] += v * v;
    }
#pragma unroll
  for (int m = 1; m <= 8; m <<= 1)
#pragma unroll
    for (int q = 0; q < 4; ++q) {
      s1[q] += __shfl_xor(s1[q], m);
      s2[q] += __shfl_xor(s2[q], m);
    }
  float mean[4], rs[4];
#pragma unroll
  for (int q = 0; q < 4; ++q) {
    mean[q] = s1[q] * (1.f / 64.f);
    float var = s2[q] * (1.f / 64.f) - mean[q] * mean[q];
    rs[q] = rsqrtf(var + EPS_);
  }
#pragma unroll
  for (int t = 0; t < 4; ++t) {
    ushort4 u;
    unsigned short* up = (unsigned short*)&u;
#pragma unroll
    for (int q = 0; q < 4; ++q)
      up[q] = f2bf((acc[t][q] - mean[q]) * rs[q] * lw[t] + lb[t]);
    *(ushort4*)&Lt[(t * 16 + l15) * 72 + wv * 16 + g * 4] = u;
  }
  __syncthreads();

  {  // coalesced residual epilogue
    const int c = tid >> 2, jq = tid & 3;
    const size_t gbase = ((size_t)(b * 64 + c) * 768 + i) * 768 + jb + jq * 16;
    float vals[16];
#pragma unroll
    for (int h = 0; h < 2; ++h) {
      bf16x8 lv = *(const bf16x8*)&Lt[c * 72 + jq * 16 + h * 8];
#pragma unroll
      for (int e = 0; e < 8; ++e)
        vals[h * 8 + e] = bf2f((unsigned short)lv[e]);
    }
#pragma unroll
    for (int v4 = 0; v4 < 4; ++v4) {
      float4 xv = *(const float4*)&xpw[gbase + v4 * 4];
      ushort4 u = make_ushort4(f2bf(xv.x + vals[v4 * 4]),
                               f2bf(xv.y + vals[v4 * 4 + 1]),
                               f2bf(xv.z + vals[v4 * 4 + 2]),
                               f2bf(xv.w + vals[v4 * 4 + 3]));
      *(ushort4*)&xp[gbase + v4 * 4] = u;
    }
  }
}

// ---------------------------------------------------------------------------
// K3: GN stats from dwconv3x3(xp): 32-row slabs, register sliding window.
// grid = 2*64*24 = 3072, 384 threads
// ---------------------------------------------------------------------------
__global__ __launch_bounds__(384) void k3_stats(
    const unsigned short* __restrict__ xp, const float* __restrict__ dww,
    float* __restrict__ stats) {
  const int tid = threadIdx.x;
  const int bx = blockIdx.x;
  const int it = bx % 24;
  const int c = (bx / 24) & 63;
  const int b = bx / (24 * 64);
  const int q = tid % 96;
  const int half = tid / 96;
  const int i0 = it * 32 + half * 8;
  const int jc = q * 8;
  const unsigned short* base = xp + (size_t)(b * 64 + c) * 768 * 768;
  float w[9];
#pragma unroll
  for (int k = 0; k < 9; ++k) w[k] = dww[c * 9 + k];

  float w0[10], w1[10], w2[10];
  loadrow10(base + (size_t)(i0 - 1) * 768, (i0 - 1) >= 0, jc, w0);
  loadrow10(base + (size_t)i0 * 768, true, jc, w1);
  float s1 = 0.f, s2 = 0.f;
#pragma unroll
  for (int rr = 0; rr < 8; ++rr) {
    const int gi = i0 + rr + 1;
    loadrow10(base + (size_t)gi * 768, gi < 768, jc, w2);
#pragma unroll
    for (int jj = 0; jj < 8; ++jj) {
      float h = w[0] * w0[jj] + w[1] * w0[jj + 1] + w[2] * w0[jj + 2] +
                w[3] * w1[jj] + w[4] * w1[jj + 1] + w[5] * w1[jj + 2] +
                w[6] * w2[jj] + w[7] * w2[jj + 1] + w[8] * w2[jj + 2];
      s1 += h;
      s2 += h * h;
    }
#pragma unroll
    for (int t = 0; t < 10; ++t) { w0[t] = w1[t]; w1[t] = w2[t]; }
  }
#pragma unroll
  for (int off = 32; off >= 1; off >>= 1) {
    s1 += __shfl_xor(s1, off);
    s2 += __shfl_xor(s2, off);
  }
  __shared__ float ws1[6], ws2[6];
  const int wid = tid >> 6;
  if ((tid & 63) == 0) { ws1[wid] = s1; ws2[wid] = s2; }
  __syncthreads();
  if (tid == 0) {
    float t1 = 0.f, t2 = 0.f;
#pragma unroll
    for (int k = 0; k < 6; ++k) { t1 += ws1[k]; t2 += ws2[k]; }
    const int grp = c >> 1;
    atomicAdd(&stats[(b * 32 + grp) * 2 + 0], t1);
    atomicAdd(&stats[(b * 32 + grp) * 2 + 1], t2);
  }
}

// ---------------------------------------------------------------------------
// K3b: per (b,c) GN scale/bias
// ---------------------------------------------------------------------------
__global__ void k3b_affine(const float* __restrict__ stats,
                           const float* __restrict__ gnw,
                           const float* __restrict__ gnb,
                           float* __restrict__ af) {
  int tid = threadIdx.x;
  if (tid >= 128) return;
  int b = tid >> 6, c = tid & 63, g = c >> 1;
  float s1 = stats[(b * 32 + g) * 2];
  float s2 = stats[(b * 32 + g) * 2 + 1];
  const float N = 2.f * 768.f * 768.f;
  float m = s1 / N;
  float v = s2 / N - m * m;
  float rs = rsqrtf(v + EPS_);
  float A = rs * gnw[c];
  af[(b * 64 + c) * 2] = A;
  af[(b * 64 + c) * 2 + 1] = gnb[c] - m * A;
}

// ---------------------------------------------------------------------------
// K4 phase-1 body: dwconv + GN affine + fast GELU -> gT; retains xp rows.
// ---------------------------------------------------------------------------
template <bool FAST>
static __device__ __forceinline__ void k4_phase1(
    const unsigned short* base, int i0, int jc, const float* w, float A,
    float Bv, int swzc, unsigned short* gT, int q, bf16x8* raw) {
  float w0[10], w1[10], w2[10];
  if (FAST) {
    ldrow10f(base + (size_t)(i0 - 1) * 768 + jc, w0);
    raw[0] = ldrow10f(base + (size_t)i0 * 768 + jc, w1);
  } else {
    loadrow10(base + (size_t)(i0 - 1) * 768, i0 >= 1, jc, w0);
    loadrow10(base + (size_t)i0 * 768, true, jc, w1);
    raw[0] = packrow(w1);
  }
#pragma unroll
  for (int r = 0; r < 4; ++r) {
    const int gi = i0 + r + 1;
    if (FAST) {
      bf16x8 rw = ldrow10f(base + (size_t)gi * 768 + jc, w2);
      if (r < 3) raw[r + 1] = rw;
    } else {
      loadrow10(base + (size_t)gi * 768, gi < 768, jc, w2);
      if (r < 3) raw[r + 1] = packrow(w2);
    }
#pragma unroll
    for (int jj = 0; jj < 8; ++jj) {
      float h = w[0] * w0[jj] + w[1] * w0[jj + 1] + w[2] * w0[jj + 2] +
                w[3] * w1[jj] + w[4] * w1[jj + 1] + w[5] * w1[jj + 2] +
                w[6] * w2[jj] + w[7] * w2[jj + 1] + w[8] * w2[jj + 2];
      float z = A * h + Bv;
      const int p = r * 64 + q * 8 + jj;
      gT[p * 72 + swzc] = f2bf(gelu_fast(z));
    }
#pragma unroll
    for (int t = 0; t < 10; ++t) { w0[t] = w1[t]; w1[t] = w2[t]; }
  }
}

// ---------------------------------------------------------------------------
// K4 v6: tile = 4 rows x 64 cols, all 64 ch. 512 threads, launch_bounds(512,4)
//   so the raw[] xp retention fits in registers (round-4 spill was the
//   (512,6) VGPR cap). No phase-3 global re-read.
// grid = 2*192*12 = 4608
// ---------------------------------------------------------------------------
__global__ __launch_bounds__(512, 4) void k4_final(
    const unsigned short* __restrict__ xp, const float* __restrict__ af,
    const float* __restrict__ dww, const float* __restrict__ pww,
    const float* __restrict__ pwb, float* __restrict__ out) {
  __shared__ __align__(16) unsigned short gT[256 * 72];  // phase3: oT[64][264]
  __shared__ __align__(16) unsigned short pwF[64 * 72];  // [co][ci]
  __shared__ float dwl[576];
  __shared__ float afl[128];
  __shared__ float pwbl[64];
  const int tid = threadIdx.x;
  const int bx = blockIdx.x;
  const int jt = bx % 12;
  const int it = (bx / 12) % 192;
  const int b = bx / (12 * 192);
  const int i0 = it * 4, j0 = jt * 64;

  {  // stage pwF (bf16)
    const int co = tid >> 3, ci0 = (tid & 7) * 8;
    float4 f0 = *(const float4*)&pww[co * 64 + ci0];
    float4 f1 = *(const float4*)&pww[co * 64 + ci0 + 4];
    *(ushort4*)&pwF[co * 72 + ci0] =
        make_ushort4(f2bf(f0.x), f2bf(f0.y), f2bf(f0.z), f2bf(f0.w));
    *(ushort4*)&pwF[co * 72 + ci0 + 4] =
        make_ushort4(f2bf(f1.x), f2bf(f1.y), f2bf(f1.z), f2bf(f1.w));
  }
  for (int idx = tid; idx < 576; idx += 512) dwl[idx] = dww[idx];
  if (tid < 128) afl[tid] = af[b * 128 + tid];
  if (tid < 64) pwbl[tid] = pwb[tid];
  __syncthreads();

  const int c = tid >> 3, q = tid & 7;
  bf16x8 raw[4];
  {  // phase 1
    const float* w = &dwl[c * 9];
    const float A = afl[c * 2], Bv = afl[c * 2 + 1];
    const unsigned short* base = xp + (size_t)(b * 64 + c) * 768 * 768;
    const int jc = j0 + q * 8;
    const int swzc = (((c >> 3) ^ q) << 3) + (c & 7);
    if (it >= 1 && it <= 190 && jt >= 1 && jt <= 10)
      k4_phase1<true>(base, i0, jc, w, A, Bv, swzc, gT, q, raw);
    else
      k4_phase1<false>(base, i0, jc, w, A, Bv, swzc, gT, q, raw);
  }
  __syncthreads();

  // phase 2: MFMA 1x1.  D[pixel][co], A = gT (swizzled chunks), B = pwF
  const int lane = tid & 63, wv = tid >> 6;
  const int g = lane >> 4, l15 = lane & 15;
  f32x4 acc[2][4];
#pragma unroll
  for (int mt = 0; mt < 2; ++mt)
#pragma unroll
    for (int nt = 0; nt < 4; ++nt) acc[mt][nt] = (f32x4){0.f, 0.f, 0.f, 0.f};

#pragma unroll
  for (int kk = 0; kk < 2; ++kk) {
    const int p0 = wv * 32 + l15;
    const int p1 = p0 + 16;
    const int cc0 = (4 * kk + g) ^ ((p0 >> 3) & 7);
    const int cc1 = (4 * kk + g) ^ ((p1 >> 3) & 7);
    bf16x8 a0 = *(const bf16x8*)&gT[p0 * 72 + cc0 * 8];
    bf16x8 a1 = *(const bf16x8*)&gT[p1 * 72 + cc1 * 8];
#pragma unroll
    for (int nt = 0; nt < 4; ++nt) {
      bf16x8 bv = *(const bf16x8*)&pwF[(nt * 16 + l15) * 72 + kk * 32 + g * 8];
      acc[0][nt] = __builtin_amdgcn_mfma_f32_16x16x32_bf16(a0, bv, acc[0][nt], 0, 0, 0);
      acc[1][nt] = __builtin_amdgcn_mfma_f32_16x16x32_bf16(a1, bv, acc[1][nt], 0, 0, 0);
    }
  }
  __syncthreads();  // all gT reads done before oT overwrite

  // phase 2b: conv results -> oT[co][264] (bf16), reusing gT memory
  unsigned short* oT = gT;
#pragma unroll
  for (int mt = 0; mt < 2; ++mt) {
#pragma unroll
    for (int nt = 0; nt < 4; ++nt) {
      const int co = nt * 16 + l15;
      const int p0 = wv * 32 + mt * 16 + g * 4;
      f32x4 a = acc[mt][nt];
      ushort4 u = make_ushort4(f2bf(a[0]), f2bf(a[1]), f2bf(a[2]), f2bf(a[3]));
      *(ushort4*)&oT[co * 264 + p0] = u;
    }
  }
  __syncthreads();

  // phase 3: out = xp(reg) + conv(oT) + bias
  {
    const float pb = pwbl[c];
    const size_t rowbase = ((size_t)(b * 64 + c) * 768 + i0) * 768 + j0 + q * 8;
#pragma unroll
    for (int r = 0; r < 4; ++r) {
      bf16x8 cv = *(const bf16x8*)&oT[c * 264 + r * 64 + q * 8];
      bf16x8 xv = raw[r];
      float4 o0, o1;
      o0.x = bf2f((unsigned short)xv[0]) + bf2f((unsigned short)cv[0]) + pb;
      o0.y = bf2f((unsigned short)xv[1]) + bf2f((unsigned short)cv[1]) + pb;
      o0.z = bf2f((unsigned short)xv[2]) + bf2f((unsigned short)cv[2]) + pb;
      o0.w = bf2f((unsigned short)xv[3]) + bf2f((unsigned short)cv[3]) + pb;
      o1.x = bf2f((unsigned short)xv[4]) + bf2f((unsigned short)cv[4]) + pb;
      o1.y = bf2f((unsigned short)xv[5]) + bf2f((unsigned short)cv[5]) + pb;
      o1.z = bf2f((unsigned short)xv[6]) + bf2f((unsigned short)cv[6]) + pb;
      o1.w = bf2f((unsigned short)xv[7]) + bf2f((unsigned short)cv[7]) + pb;
      float* op = out + rowbase + (size_t)r * 768;
      *(float4*)op = o0;
      *(float4*)(op + 4) = o1;
    }
  }
}

// ---------------------------------------------------------------------------
extern "C" void kernel_launch(void* const* d_in, const int* in_sizes, int n_in,
                              void* d_out, int out_size, void* d_ws,
                              size_t ws_size, hipStream_t stream) {
  const float* x_pw = (const float*)d_in[0];
  const float* x    = (const float*)d_in[1];
  const float* Wsl  = (const float*)d_in[2];
  const float* bsl  = (const float*)d_in[3];
  const float* Wop  = (const float*)d_in[4];
  const float* bop  = (const float*)d_in[5];
  const float* lnw  = (const float*)d_in[6];
  const float* lnb  = (const float*)d_in[7];
  const float* dww  = (const float*)d_in[8];
  const float* gnw  = (const float*)d_in[9];
  const float* gnb  = (const float*)d_in[10];
  const float* pww  = (const float*)d_in[11];
  const float* pwb  = (const float*)d_in[12];
  float* out = (float*)d_out;

  char* ws = (char*)d_ws;
  unsigned short* a_bf = (unsigned short*)ws;             // 196608 B
  float* stats  = (float*)(ws + 196608);                  // 512 B
  float* affine = (float*)(ws + 197120);                  // 1024 B
  unsigned short* xpbuf = (unsigned short*)(ws + 262144); // 151 MB bf16

  hipMemsetAsync(stats, 0, 512, stream);
  k1_proj<<<24, 256, 0, stream>>>(x, Wsl, bsl, a_bf);
  k2_outer<<<2 * 768 * 12, 256, 0, stream>>>(x_pw, a_bf, Wop, bop, lnw, lnb,
                                             xpbuf);
  k3_stats<<<2 * 64 * 24, 384, 0, stream>>>(xpbuf, dww, stats);
  k3b_affine<<<1, 128, 0, stream>>>(stats, gnw, gnb, affine);
  k4_final<<<2 * 192 * 12, 512, 0, stream>>>(xpbuf, affine, dww, pww, pwb, out);
}